// Round 1
// baseline (201.322 us; speedup 1.0000x reference)
//
#include <hip/hip_runtime.h>

// LightningIndexer: out[b,q,k] = sum_h w_h * relu( (xWq^T+bq)[b,q,h,:] . (xWk^T+bk)[b,k,h,:] )
// B=2, S=4096, Dmodel=1024, H=4, HD=64.
// Pipeline: K0 convert W->bf16; K1 bf16-MFMA projection GEMM -> Qb,Kb (bf16, ws);
//           K2 per-head QK^T + relu + weighted sum -> out fp32.

typedef __bf16 bf16;
typedef __bf16 bf16x4 __attribute__((ext_vector_type(4)));
typedef __bf16 bf16x8 __attribute__((ext_vector_type(8)));
typedef float f32x4 __attribute__((ext_vector_type(4)));

#define NB 2
#define SEQ 4096
#define DMODEL 1024
#define NHEAD 4
#define HDIM 64
#define NPROJ 256       // NHEAD*HDIM
#define MTOT 8192       // NB*SEQ

// async global->LDS, 16B per lane; LDS dest = wave-uniform base + lane*16
__device__ __forceinline__ void async16(const void* g, void* l) {
  __builtin_amdgcn_global_load_lds(
      (const __attribute__((address_space(1))) void*)g,
      (__attribute__((address_space(3))) void*)l, 16, 0, 0);
}

// ---------------- K0: convert Wq, Wk fp32 -> bf16 ----------------
__global__ __launch_bounds__(256) void k_convert(const float* __restrict__ wq,
                                                 const float* __restrict__ wk,
                                                 bf16* __restrict__ wqb,
                                                 bf16* __restrict__ wkb) {
  int i = blockIdx.x * 256 + threadIdx.x;  // 65536 float4 groups of 256*1024 floats
  float4 a = ((const float4*)wq)[i];
  bf16x4 oa = {(bf16)a.x, (bf16)a.y, (bf16)a.z, (bf16)a.w};
  ((bf16x4*)wqb)[i] = oa;
  float4 b = ((const float4*)wk)[i];
  bf16x4 ob = {(bf16)b.x, (bf16)b.y, (bf16)b.z, (bf16)b.w};
  ((bf16x4*)wkb)[i] = ob;
}

// ---------------- K1: projection GEMM ----------------
// out[m,n] = sum_k x[m,k]*W[n,k] + bias[n], stored bf16.
// Block tile: BM=64, BN=256 (full N), BK=64. grid (128, 2): y selects Q/K.
// 4 waves, each 64x64 quadrant (cols w*64..w*64+63), 4x4 grid of 16x16x32 MFMA.
__global__ __launch_bounds__(256, 3) void k_proj(
    const float* __restrict__ x, const bf16* __restrict__ wqb,
    const bf16* __restrict__ wkb, const float* __restrict__ qbias,
    const float* __restrict__ kbias, bf16* __restrict__ Qb,
    bf16* __restrict__ Kb) {
  // As: padded rows (72 bf16) -> fragment reads land 2-way (free) on banks.
  // Bs: global_load_lds (contiguous 128B rows) with XOR-swizzled source chunks:
  //     LDS slot (r, c') holds global chunk c' ^ (r&7).
  __shared__ __align__(16) bf16 As[64 * 72];
  __shared__ __align__(16) bf16 Bs[256 * 64];
  const int t = threadIdx.x;
  const int lane = t & 63, w = t >> 6;
  const int m16 = lane & 15, q = lane >> 4;
  const int m0 = blockIdx.x * 64;
  const int z = blockIdx.y;
  const bf16* W = z ? wkb : wqb;

  f32x4 acc[4][4];
#pragma unroll
  for (int i = 0; i < 4; i++)
#pragma unroll
    for (int j = 0; j < 4; j++) acc[i][j] = {0.f, 0.f, 0.f, 0.f};

  for (int kt = 0; kt < 16; kt++) {
    // async stage W slab [256 rows][64 bf16] (issue first, overlap with A conversion)
#pragma unroll
    for (int p = 0; p < 8; p++) {
      int n0 = p * 32 + w * 8;                 // wave-uniform row base (8 rows/call)
      int r = n0 + (lane >> 3);
      int c = (lane & 7) ^ (r & 7);            // swizzled source chunk
      async16(W + (size_t)r * DMODEL + kt * 64 + c * 8, Bs + n0 * 64);
    }
    // stage x tile [64][64] fp32 -> bf16 via registers
#pragma unroll
    for (int p = 0; p < 4; p++) {
      int r = p * 16 + (t >> 4);
      int c = (t & 15) * 4;
      float4 v = *(const float4*)(x + (size_t)(m0 + r) * DMODEL + kt * 64 + c);
      bf16x4 o = {(bf16)v.x, (bf16)v.y, (bf16)v.z, (bf16)v.w};
      *(bf16x4*)(As + r * 72 + c) = o;
    }
    __builtin_amdgcn_s_waitcnt(0);
    __syncthreads();

#pragma unroll
    for (int s = 0; s < 2; s++) {
      bf16x8 a[4], b[4];
#pragma unroll
      for (int mt = 0; mt < 4; mt++)
        a[mt] = *(const bf16x8*)(As + (mt * 16 + m16) * 72 + s * 32 + q * 8);
#pragma unroll
      for (int nt = 0; nt < 4; nt++) {
        int n = w * 64 + nt * 16 + m16;
        int cc = (4 * s + q) ^ (n & 7);
        b[nt] = *(const bf16x8*)(Bs + n * 64 + cc * 8);
      }
#pragma unroll
      for (int mt = 0; mt < 4; mt++)
#pragma unroll
        for (int nt = 0; nt < 4; nt++)
          acc[mt][nt] = __builtin_amdgcn_mfma_f32_16x16x32_bf16(
              a[mt], b[nt], acc[mt][nt], 0, 0, 0);
    }
    __syncthreads();
  }

  const float* bias = z ? kbias : qbias;
  bf16* outp = z ? Kb : Qb;
#pragma unroll
  for (int nt = 0; nt < 4; nt++) {
    int col = w * 64 + nt * 16 + m16;   // C/D: col = lane&15
    float bv = bias[col];
#pragma unroll
    for (int mt = 0; mt < 4; mt++) {
      int row0 = m0 + mt * 16 + q * 4;  // C/D: row = quad*4 + reg
#pragma unroll
      for (int e = 0; e < 4; e++)
        outp[(size_t)(row0 + e) * NPROJ + col] = (bf16)(acc[mt][nt][e] + bv);
    }
  }
}

// ---------------- K2: scores ----------------
// grid (32 ktiles, 32 qtiles, 2 batches); block 256 threads; out tile 128x128.
// Per head: stage Q/K head-slices [128][64] bf16 (swizzled async16), per wave
// 64x64 quadrant, S = QK^T via 2-chain K=32 MFMAs, fold accf += w_h*relu(S).
__global__ __launch_bounds__(256, 2) void k_scores(
    const bf16* __restrict__ Qb, const bf16* __restrict__ Kb,
    const float* __restrict__ iw, float* __restrict__ out) {
  __shared__ __align__(16) bf16 Qs[128 * 64];
  __shared__ __align__(16) bf16 Ks[128 * 64];
  const int t = threadIdx.x;
  const int lane = t & 63, w = t >> 6;
  const int m16 = lane & 15, q = lane >> 4;
  const int kx = blockIdx.x, qy = blockIdx.y, bz = blockIdx.z;
  const int rh = (w >> 1) * 64, ch = (w & 1) * 64;  // wave quadrant

  f32x4 accf[4][4];
#pragma unroll
  for (int i = 0; i < 4; i++)
#pragma unroll
    for (int j = 0; j < 4; j++) accf[i][j] = {0.f, 0.f, 0.f, 0.f};

  const size_t qbase = ((size_t)bz * SEQ + (size_t)qy * 128) * NPROJ;
  const size_t kbase = ((size_t)bz * SEQ + (size_t)kx * 128) * NPROJ;

  for (int h = 0; h < NHEAD; h++) {
#pragma unroll
    for (int p = 0; p < 4; p++) {
      int r0 = w * 32 + p * 8;            // wave-uniform base rows
      int r = r0 + (lane >> 3);
      int c = (lane & 7) ^ (r & 7);       // swizzled source chunk
      async16(Qb + qbase + (size_t)r * NPROJ + h * 64 + c * 8, Qs + r0 * 64);
      async16(Kb + kbase + (size_t)r * NPROJ + h * 64 + c * 8, Ks + r0 * 64);
    }
    __builtin_amdgcn_s_waitcnt(0);
    __syncthreads();

    float wh = iw[h];
    bf16x8 b0[4], b1[4];
#pragma unroll
    for (int nt = 0; nt < 4; nt++) {
      int n = ch + nt * 16 + m16;
      b0[nt] = *(const bf16x8*)(Ks + n * 64 + ((q) ^ (n & 7)) * 8);
      b1[nt] = *(const bf16x8*)(Ks + n * 64 + ((4 + q) ^ (n & 7)) * 8);
    }
#pragma unroll
    for (int mt = 0; mt < 4; mt++) {
      int m = rh + mt * 16 + m16;
      bf16x8 a0 = *(const bf16x8*)(Qs + m * 64 + ((q) ^ (m & 7)) * 8);
      bf16x8 a1 = *(const bf16x8*)(Qs + m * 64 + ((4 + q) ^ (m & 7)) * 8);
#pragma unroll
      for (int nt = 0; nt < 4; nt++) {
        f32x4 tacc = {0.f, 0.f, 0.f, 0.f};
        tacc = __builtin_amdgcn_mfma_f32_16x16x32_bf16(a0, b0[nt], tacc, 0, 0, 0);
        tacc = __builtin_amdgcn_mfma_f32_16x16x32_bf16(a1, b1[nt], tacc, 0, 0, 0);
#pragma unroll
        for (int e = 0; e < 4; e++)
          accf[mt][nt][e] += wh * fmaxf(tacc[e], 0.f);
      }
    }
    __syncthreads();
  }

#pragma unroll
  for (int mt = 0; mt < 4; mt++)
#pragma unroll
    for (int e = 0; e < 4; e++) {
      int row = qy * 128 + rh + mt * 16 + q * 4 + e;
      size_t ob = ((size_t)bz * SEQ + row) * SEQ + (size_t)kx * 128 + ch;
#pragma unroll
      for (int nt = 0; nt < 4; nt++)
        out[ob + nt * 16 + m16] = accf[mt][nt][e];
    }
}

extern "C" void kernel_launch(void* const* d_in, const int* in_sizes, int n_in,
                              void* d_out, int out_size, void* d_ws, size_t ws_size,
                              hipStream_t stream) {
  const float* x  = (const float*)d_in[0];   // [2,4096,1024]
  const float* wq = (const float*)d_in[1];   // [256,1024]
  const float* qb = (const float*)d_in[2];   // [256]
  const float* wk = (const float*)d_in[3];   // [256,1024]
  const float* kb = (const float*)d_in[4];   // [256]
  const float* iw = (const float*)d_in[5];   // [4]
  float* out = (float*)d_out;                // [2,4096,4096]

  // workspace layout (9,437,184 B total)
  char* ws = (char*)d_ws;
  bf16* wqb = (bf16*)ws;                               // 512 KB
  bf16* wkb = (bf16*)(ws + 524288);                    // 512 KB
  bf16* Qb  = (bf16*)(ws + 1048576);                   // 4 MB  [8192][256]
  bf16* Kb  = (bf16*)(ws + 1048576 + 4194304);         // 4 MB  [8192][256]

  k_convert<<<256, 256, 0, stream>>>(wq, wk, wqb, wkb);
  k_proj<<<dim3(128, 2, 1), 256, 0, stream>>>(x, wqb, wkb, qb, kb, Qb, Kb);
  k_scores<<<dim3(32, 32, 2), 256, 0, stream>>>(Qb, Kb, iw, out);
}